// Round 11
// baseline (536.970 us; speedup 1.0000x reference)
//
#include <hip/hip_runtime.h>
#include <hip/hip_bf16.h>

#define H 4
#define D 256
#define NEG_SLOPE 0.2f

typedef __attribute__((ext_vector_type(8))) _Float16 f16x8;
typedef __attribute__((ext_vector_type(4))) _Float16 f16x4;
typedef __attribute__((ext_vector_type(4))) float f32x4;

// ---- merged f32->f16 convert: x[N,128] + W0[128*256] + W1..4[256*256] ----
__global__ void k_cvt_all(const float* __restrict__ x,
                          const float* __restrict__ w0, const float* __restrict__ w1,
                          const float* __restrict__ w2, const float* __restrict__ w3,
                          const float* __restrict__ w4,
                          _Float16* __restrict__ xf, _Float16* __restrict__ wf,
                          int nx4) {
    int i = blockIdx.x * blockDim.x + threadIdx.x;
    const int nW0 = 128 * 256 / 4, nW = 256 * 256 / 4;
    const float* src;
    _Float16* dst;
    int off;
    if (i < nx4) { src = x; dst = xf; off = i; }
    else {
        i -= nx4;
        if (i < nW0) { src = w0; dst = wf; off = i; }
        else {
            i -= nW0;
            int l = i / nW, r2 = i % nW;
            if (l >= 4) return;
            const float* ws[4] = {w1, w2, w3, w4};
            src = ws[l];
            dst = wf + 128 * 256 + (size_t)l * 256 * 256;
            off = r2;
        }
    }
    float4 v = ((const float4*)src)[off];
    f16x4 o = {(_Float16)v.x, (_Float16)v.y, (_Float16)v.z, (_Float16)v.w};
    *(f16x4*)&dst[(size_t)off * 4] = o;
}

// ---- MFMA GEMM v3: BK=32, reg prefetch issued AFTER barrier-2 ----
// (loads drain at next iter's barrier-1, i.e. after the MFMA phase)
template<int K>
__global__ __launch_bounds__(256) void k_gemm_mfma(
        const _Float16* __restrict__ xf, const _Float16* __restrict__ wf,
        const float* __restrict__ att_src, const float* __restrict__ att_dst,
        _Float16* __restrict__ hmat, float* __restrict__ alpha_src,
        float* __restrict__ alpha_dst, int nrows) {
    const int NSTEP = K / 32;
    __shared__ _Float16 sx[64][40];     // pad 32->40 (80B rows)
    __shared__ _Float16 sw[256][40];
    int t = threadIdx.x;
    int w = t >> 6, l = t & 63;
    int r = l & 15, q = l >> 4;
    int row0 = blockIdx.x * 64;
    int srow = t >> 2;                  // staging row 0..63
    int scol = (t & 3) * 8;             // 8-elem col slot
    int gxr  = row0 + srow;
    bool xok = (gxr < nrows);

    f32x4 acc[16];
    #pragma unroll
    for (int cf = 0; cf < 16; ++cf) acc[cf] = (f32x4){0.f, 0.f, 0.f, 0.f};

    // prologue: tile 0 -> regs
    uint4 ldx, ldw[4];
    ldx = xok ? *(const uint4*)&xf[(size_t)gxr * K + scol] : make_uint4(0, 0, 0, 0);
    #pragma unroll
    for (int i = 0; i < 4; ++i)
        ldw[i] = *(const uint4*)&wf[(size_t)(srow + i * 64) * K + scol];

    for (int step = 0; step < NSTEP; ++step) {
        __syncthreads();               // prev tile reads done; prefetch drained here
        *(uint4*)&sx[srow][scol] = ldx;
        #pragma unroll
        for (int i = 0; i < 4; ++i)
            *(uint4*)&sw[srow + i * 64][scol] = ldw[i];
        __syncthreads();               // tile ready
        // prefetch next tile AFTER the barrier: overlaps the MFMA phase
        if (step + 1 < NSTEP) {
            int k0 = (step + 1) * 32;
            ldx = xok ? *(const uint4*)&xf[(size_t)gxr * K + k0 + scol]
                      : make_uint4(0, 0, 0, 0);
            #pragma unroll
            for (int i = 0; i < 4; ++i)
                ldw[i] = *(const uint4*)&wf[(size_t)(srow + i * 64) * K + k0 + scol];
        }
        f16x8 a = *(f16x8*)&sx[w * 16 + r][q * 8];
        #pragma unroll
        for (int cf = 0; cf < 16; ++cf) {
            f16x8 b = *(f16x8*)&sw[cf * 16 + r][q * 8];
            acc[cf] = __builtin_amdgcn_mfma_f32_16x16x32_f16(a, b, acc[cf], 0, 0, 0);
        }
    }
    // store h (fp16): D[row=(q*4+i)][col=cf*16+r]
    #pragma unroll
    for (int cf = 0; cf < 16; ++cf) {
        #pragma unroll
        for (int i = 0; i < 4; ++i) {
            int gr = row0 + w * 16 + q * 4 + i;
            if (gr < nrows) hmat[(size_t)gr * D + cf * 16 + r] = (_Float16)acc[cf][i];
        }
    }
    // fused alpha epilogue -> [node*4 + head]
    float asv[16], adv[16];
    #pragma unroll
    for (int cf = 0; cf < 16; ++cf) {
        asv[cf] = att_src[cf * 16 + r];
        adv[cf] = att_dst[cf * 16 + r];
    }
    #pragma unroll
    for (int i = 0; i < 4; ++i) {
        #pragma unroll
        for (int h4 = 0; h4 < 4; ++h4) {
            float ps = 0.f, pd = 0.f;
            #pragma unroll
            for (int j = 0; j < 4; ++j) {
                int cf = h4 * 4 + j;
                ps += acc[cf][i] * asv[cf];
                pd += acc[cf][i] * adv[cf];
            }
            #pragma unroll
            for (int m = 1; m < 16; m <<= 1) {
                ps += __shfl_xor(ps, m);
                pd += __shfl_xor(pd, m);
            }
            int gr = row0 + w * 16 + q * 4 + i;
            if (r == 0 && gr < nrows) {
                alpha_src[gr * 4 + h4] = ps;
                alpha_dst[gr * 4 + h4] = pd;
            }
        }
    }
}

// ---------------- CSR build (graph constant across layers) ----------------
__global__ void k_deg(const int* __restrict__ ei, int E, int E2, int* __restrict__ deg) {
    int e = blockIdx.x * blockDim.x + threadIdx.x;
    if (e >= E2) return;
    int de = (e < E) ? ei[E + e] : (e - E);
    atomicAdd(&deg[de], 1);
}

__global__ void k_scan_block(const int* __restrict__ deg, int* __restrict__ incl,
                             int* __restrict__ bsum, int n) {
    __shared__ int sd[256];
    int t = threadIdx.x;
    int i = blockIdx.x * 256 + t;
    int v = (i < n) ? deg[i] : 0;
    sd[t] = v;
    __syncthreads();
    for (int off = 1; off < 256; off <<= 1) {
        int add = (t >= off) ? sd[t - off] : 0;
        __syncthreads();
        sd[t] += add;
        __syncthreads();
    }
    if (i < n) incl[i] = sd[t];
    if (t == 255) bsum[blockIdx.x] = sd[255];
}

__global__ void k_scan_bsum(int* __restrict__ bsum, int nb) {
    __shared__ int sd[256];
    int t = threadIdx.x;
    int v = (t < nb) ? bsum[t] : 0;
    sd[t] = v;
    __syncthreads();
    for (int off = 1; off < 256; off <<= 1) {
        int add = (t >= off) ? sd[t - off] : 0;
        __syncthreads();
        sd[t] += add;
        __syncthreads();
    }
    if (t < nb) bsum[t] = sd[t] - v;
}

__global__ void k_rowptr(const int* __restrict__ incl, const int* __restrict__ deg,
                         const int* __restrict__ boff, int* __restrict__ row_ptr,
                         int n, int total) {
    int i = blockIdx.x * blockDim.x + threadIdx.x;
    if (i < n) row_ptr[i] = incl[i] - deg[i] + boff[i >> 8];
    if (i == 0) row_ptr[n] = total;
}

__global__ void k_scatter(const int* __restrict__ ei, int E, int E2,
                          const int* __restrict__ row_ptr, int* __restrict__ cursor,
                          int* __restrict__ csr_src) {
    int e = blockIdx.x * blockDim.x + threadIdx.x;
    if (e >= E2) return;
    int se, de;
    if (e < E) { se = ei[e]; de = ei[E + e]; }
    else       { se = e - E; de = se; }
    int pos = atomicAdd(&cursor[de], 1);
    csr_src[row_ptr[de] + pos] = se;
}

// ---- aggregation: wave per node; lane=(e2,c); 16 edges in flight; f16x8 ----
__global__ __launch_bounds__(256) void k_aggregate(const _Float16* __restrict__ hmat,
        const int* __restrict__ row_ptr, const int* __restrict__ csr_src,
        const float* __restrict__ alpha_src, const float* __restrict__ alpha_dst,
        const float* __restrict__ bias, float* __restrict__ outf,
        _Float16* __restrict__ outx, int relu, int nrows) {
    int node = (blockIdx.x * 256 + threadIdx.x) >> 6;
    if (node >= nrows) return;
    int lane = threadIdx.x & 63;
    int e2 = lane >> 5;            // edge-slot half (0/1)
    int c  = lane & 31;            // channel octet: channels c*8..c*8+7
    int head = c >> 3;
    int st = row_ptr[node], en = row_ptr[node + 1];
    int deg = en - st;
    float a_d = alpha_dst[node * 4 + head];
    float acc[8] = {};
    float ssum = 0.f;
    for (int b = 0; b < deg; b += 16) {
        int sn[8];
        #pragma unroll
        for (int j = 0; j < 8; ++j) {
            int e = b + e2 * 8 + j;
            int li = st + (e < deg ? e : deg - 1);
            sn[j] = csr_src[li];
        }
        f16x8 hv[8];
        #pragma unroll
        for (int j = 0; j < 8; ++j)
            hv[j] = *(const f16x8*)&hmat[(size_t)sn[j] * D + c * 8];
        float as[8];
        #pragma unroll
        for (int j = 0; j < 8; ++j) as[j] = alpha_src[sn[j] * 4 + head];
        #pragma unroll
        for (int j = 0; j < 8; ++j) {
            int e = b + e2 * 8 + j;
            float a = as[j] + a_d;
            a = a > 0.f ? a : NEG_SLOPE * a;
            float ex = (e < deg) ? __expf(a) : 0.f;
            ssum += ex;
            #pragma unroll
            for (int k = 0; k < 8; ++k) acc[k] += ex * (float)hv[j][k];
        }
    }
    ssum += __shfl_xor(ssum, 32);
    #pragma unroll
    for (int k = 0; k < 8; ++k) acc[k] += __shfl_xor(acc[k], 32);
    if (e2 == 0) {
        float sinv = 1.f / (ssum + 1e-16f);
        float4 b0 = *(const float4*)&bias[c * 8];
        float4 b1 = *(const float4*)&bias[c * 8 + 4];
        float o[8];
        o[0] = acc[0] * sinv + b0.x; o[1] = acc[1] * sinv + b0.y;
        o[2] = acc[2] * sinv + b0.z; o[3] = acc[3] * sinv + b0.w;
        o[4] = acc[4] * sinv + b1.x; o[5] = acc[5] * sinv + b1.y;
        o[6] = acc[6] * sinv + b1.z; o[7] = acc[7] * sinv + b1.w;
        if (relu) {
            #pragma unroll
            for (int k = 0; k < 8; ++k) o[k] = fmaxf(o[k], 0.f);
        }
        if (outx) {
            f16x8 o8 = {(_Float16)o[0], (_Float16)o[1], (_Float16)o[2], (_Float16)o[3],
                        (_Float16)o[4], (_Float16)o[5], (_Float16)o[6], (_Float16)o[7]};
            *(f16x8*)&outx[(size_t)node * D + c * 8] = o8;
        } else {
            *(float4*)&outf[(size_t)node * D + c * 8] =
                make_float4(o[0], o[1], o[2], o[3]);
            *(float4*)&outf[(size_t)node * D + c * 8 + 4] =
                make_float4(o[4], o[5], o[6], o[7]);
        }
    }
}

extern "C" void kernel_launch(void* const* d_in, const int* in_sizes, int n_in,
                              void* d_out, int out_size, void* d_ws, size_t ws_size,
                              hipStream_t stream) {
    const float* x = (const float*)d_in[0];
    const int* ei = (const int*)d_in[1];
    const int N  = in_sizes[0] / 128;   // 50000
    const int E  = in_sizes[1] / 2;     // 400000
    const int E2 = E + N;               // + self loops

    char* wsp = (char*)d_ws;
    size_t off = 0;
    auto alloc = [&](size_t bytes) -> void* {
        void* p = wsp + off;
        off += (bytes + 255) & ~(size_t)255;
        return p;
    };
    _Float16* bufH  = (_Float16*)alloc((size_t)N * D * 2);     // 25.6 MB
    _Float16* xf16  = (_Float16*)alloc((size_t)N * D * 2);     // 25.6 MB
    _Float16* wf16  = (_Float16*)alloc((size_t)(128 * 256 + 4 * 256 * 256) * 2);
    float* alpha_src = (float*)alloc((size_t)N * H * 4);
    float* alpha_dst = (float*)alloc((size_t)N * H * 4);
    int*   deg       = (int*)alloc((size_t)N * 4);
    int*   incl      = (int*)alloc((size_t)N * 4);
    int*   bsum      = (int*)alloc(256 * 4);
    int*   row_ptr   = (int*)alloc((size_t)(N + 1) * 4);
    int*   cursor    = (int*)alloc((size_t)N * 4);
    int*   csr_src   = (int*)alloc((size_t)E2 * 4);
    (void)ws_size;

    hipMemsetAsync(deg, 0, (size_t)N * 4, stream);
    hipMemsetAsync(cursor, 0, (size_t)N * 4, stream);

    // merged convert: x + all 5 W
    int nx4 = N * 128 / 4;
    int tot4 = nx4 + 128 * 256 / 4 + 4 * (256 * 256 / 4);
    k_cvt_all<<<(tot4 + 255) / 256, 256, 0, stream>>>(
        x, (const float*)d_in[2], (const float*)d_in[6], (const float*)d_in[10],
        (const float*)d_in[14], (const float*)d_in[18], xf16, wf16, nx4);

    // CSR by dst
    int egrid = (E2 + 255) / 256;
    k_deg<<<egrid, 256, 0, stream>>>(ei, E, E2, deg);
    int nb = (N + 255) / 256;
    k_scan_block<<<nb, 256, 0, stream>>>(deg, incl, bsum, N);
    k_scan_bsum<<<1, 256, 0, stream>>>(bsum, nb);
    k_rowptr<<<nb, 256, 0, stream>>>(incl, deg, bsum, row_ptr, N, E2);
    k_scatter<<<egrid, 256, 0, stream>>>(ei, E, E2, row_ptr, cursor, csr_src);

    int ggrid = (N + 63) / 64;
    int agrid = (N + 3) / 4;
    for (int l = 0; l < 5; ++l) {
        const float* as_ = (const float*)d_in[3 + 4 * l];
        const float* ad_ = (const float*)d_in[4 + 4 * l];
        const float* bs_ = (const float*)d_in[5 + 4 * l];
        const _Float16* wl = (l == 0) ? wf16
                           : wf16 + 128 * 256 + (size_t)(l - 1) * 256 * 256;

        if (l == 0)
            k_gemm_mfma<128><<<ggrid, 256, 0, stream>>>(xf16, wl, as_, ad_,
                                                        bufH, alpha_src, alpha_dst, N);
        else
            k_gemm_mfma<256><<<ggrid, 256, 0, stream>>>(xf16, wl, as_, ad_,
                                                        bufH, alpha_src, alpha_dst, N);

        int last = (l == 4);
        k_aggregate<<<agrid, 256, 0, stream>>>(bufH, row_ptr, csr_src,
                                               alpha_src, alpha_dst, bs_,
                                               last ? (float*)d_out : nullptr,
                                               last ? nullptr : xf16,
                                               last ? 0 : 1, N);
    }
}

// Round 12
// 423.418 us; speedup vs baseline: 1.2682x; 1.2682x over previous
//
#include <hip/hip_runtime.h>
#include <hip/hip_bf16.h>

#define H 4
#define D 256
#define NEG_SLOPE 0.2f

typedef __attribute__((ext_vector_type(8))) _Float16 f16x8;
typedef __attribute__((ext_vector_type(4))) _Float16 f16x4;
typedef __attribute__((ext_vector_type(4))) float f32x4;

// ---------------- f32 -> f16 convert (x) ----------------
__global__ void k_cvt(const float* __restrict__ in, _Float16* __restrict__ out, int n4) {
    int i = blockIdx.x * blockDim.x + threadIdx.x;
    if (i >= n4) return;
    float4 v = ((const float4*)in)[i];
    f16x4 o = {(_Float16)v.x, (_Float16)v.y, (_Float16)v.z, (_Float16)v.w};
    *(f16x4*)&out[(size_t)i * 4] = o;
}

// ---- W -> fp16 in MFMA fragment order ----
// wfrag[((split*8 + cf)*NKS + ks)*64 + l] (f16x8 chunks) =
//   W[(split*8+cf)*16 + (l&15)][ks*32 + (l>>4)*8 + j]
template<int K>
__global__ void k_cvt_wfrag(const float* __restrict__ W, _Float16* __restrict__ wfrag) {
    const int NKS = K / 32;
    int idx = blockIdx.x * blockDim.x + threadIdx.x;   // (split*8+cf)*NKS*64 + ks*64 + l
    if (idx >= 16 * NKS * 64) return;
    int l  = idx & 63;
    int ks = (idx >> 6) % NKS;
    int c16 = idx / (NKS * 64);        // split*8+cf = global col-frag 0..15
    int col = c16 * 16 + (l & 15);
    int k0  = ks * 32 + (l >> 4) * 8;
    const float* src = &W[(size_t)col * K + k0];
    float4 v0 = *(const float4*)src;
    float4 v1 = *(const float4*)(src + 4);
    f16x8 o = {(_Float16)v0.x, (_Float16)v0.y, (_Float16)v0.z, (_Float16)v0.w,
               (_Float16)v1.x, (_Float16)v1.y, (_Float16)v1.z, (_Float16)v1.w};
    *(f16x8*)&wfrag[(size_t)idx * 8] = o;
}

// ---- MFMA GEMM v4: W-frag in LDS (staged once), x direct, zero K-loop barriers ----
// grid = (ceil(N/64), 2); block 256 thr / 4 waves; wave = 16 rows x 128 cols.
template<int K>
__global__ __launch_bounds__(256) void k_gemm_mfma(
        const _Float16* __restrict__ xf, const _Float16* __restrict__ wfrag,
        const float* __restrict__ att_src, const float* __restrict__ att_dst,
        _Float16* __restrict__ hmat, float* __restrict__ alpha_src,
        float* __restrict__ alpha_dst, int nrows) {
    const int NKS = K / 32;
    __shared__ _Float16 sw[8 * NKS * 64 * 8];          // 64KB (K=256) / 32KB (K=128)
    int t = threadIdx.x;
    int w = t >> 6, l = t & 63;
    int r = l & 15, q = l >> 4;
    int row0  = blockIdx.x * 64;
    int split = blockIdx.y;                            // col half: cols split*128..+127

    // stage W-half fragments -> LDS (contiguous copy, coalesced, conflict-free)
    {
        const uint4* wsrc = (const uint4*)(wfrag + (size_t)split * 8 * NKS * 64 * 8);
        uint4* wdst = (uint4*)sw;
        const int nchunk = 8 * NKS * 64;               // 16B chunks
        #pragma unroll
        for (int i = 0; i < nchunk / 256; ++i)
            wdst[i * 256 + t] = wsrc[i * 256 + t];
    }

    // a-frags direct from global (row read exactly once grid-wide per split)
    int gr_a = row0 + w * 16 + r;
    bool aok = (gr_a < nrows);
    f16x8 a[NKS];
    #pragma unroll
    for (int ks = 0; ks < NKS; ++ks) {
        if (aok) a[ks] = *(const f16x8*)&xf[(size_t)gr_a * K + ks * 32 + q * 8];
        else     a[ks] = (f16x8){0, 0, 0, 0, 0, 0, 0, 0};
    }

    __syncthreads();                                   // W tile ready (only barrier)

    f32x4 acc[8];
    #pragma unroll
    for (int cf = 0; cf < 8; ++cf) acc[cf] = (f32x4){0.f, 0.f, 0.f, 0.f};
    #pragma unroll
    for (int cf = 0; cf < 8; ++cf) {
        f16x8 b[NKS];
        #pragma unroll
        for (int ks = 0; ks < NKS; ++ks)
            b[ks] = *(f16x8*)&sw[(size_t)((cf * NKS + ks) * 64 + l) * 8];
        #pragma unroll
        for (int ks = 0; ks < NKS; ++ks)
            acc[cf] = __builtin_amdgcn_mfma_f32_16x16x32_f16(a[ks], b[ks], acc[cf], 0, 0, 0);
    }

    // store h: col = split*128 + cf*16 + r, row = row0 + w*16 + q*4 + i
    #pragma unroll
    for (int cf = 0; cf < 8; ++cf) {
        #pragma unroll
        for (int i = 0; i < 4; ++i) {
            int gr = row0 + w * 16 + q * 4 + i;
            if (gr < nrows)
                hmat[(size_t)gr * D + split * 128 + cf * 16 + r] = (_Float16)acc[cf][i];
        }
    }
    // fused alpha: this block covers heads split*2 (cf 0..3) and split*2+1 (cf 4..7)
    float asv[8], adv[8];
    #pragma unroll
    for (int cf = 0; cf < 8; ++cf) {
        asv[cf] = att_src[split * 128 + cf * 16 + r];
        adv[cf] = att_dst[split * 128 + cf * 16 + r];
    }
    #pragma unroll
    for (int i = 0; i < 4; ++i) {
        #pragma unroll
        for (int hh = 0; hh < 2; ++hh) {
            float ps = 0.f, pd = 0.f;
            #pragma unroll
            for (int j = 0; j < 4; ++j) {
                int cf = hh * 4 + j;
                ps += acc[cf][i] * asv[cf];
                pd += acc[cf][i] * adv[cf];
            }
            #pragma unroll
            for (int m = 1; m < 16; m <<= 1) {
                ps += __shfl_xor(ps, m);
                pd += __shfl_xor(pd, m);
            }
            int gr = row0 + w * 16 + q * 4 + i;
            if (r == 0 && gr < nrows) {
                alpha_src[gr * 4 + split * 2 + hh] = ps;
                alpha_dst[gr * 4 + split * 2 + hh] = pd;
            }
        }
    }
}

// ---------------- CSR build (graph constant across layers) ----------------
__global__ void k_deg(const int* __restrict__ ei, int E, int E2, int* __restrict__ deg) {
    int e = blockIdx.x * blockDim.x + threadIdx.x;
    if (e >= E2) return;
    int de = (e < E) ? ei[E + e] : (e - E);
    atomicAdd(&deg[de], 1);
}

__global__ void k_scan_block(const int* __restrict__ deg, int* __restrict__ incl,
                             int* __restrict__ bsum, int n) {
    __shared__ int sd[256];
    int t = threadIdx.x;
    int i = blockIdx.x * 256 + t;
    int v = (i < n) ? deg[i] : 0;
    sd[t] = v;
    __syncthreads();
    for (int off = 1; off < 256; off <<= 1) {
        int add = (t >= off) ? sd[t - off] : 0;
        __syncthreads();
        sd[t] += add;
        __syncthreads();
    }
    if (i < n) incl[i] = sd[t];
    if (t == 255) bsum[blockIdx.x] = sd[255];
}

__global__ void k_scan_bsum(int* __restrict__ bsum, int nb) {
    __shared__ int sd[256];
    int t = threadIdx.x;
    int v = (t < nb) ? bsum[t] : 0;
    sd[t] = v;
    __syncthreads();
    for (int off = 1; off < 256; off <<= 1) {
        int add = (t >= off) ? sd[t - off] : 0;
        __syncthreads();
        sd[t] += add;
        __syncthreads();
    }
    if (t < nb) bsum[t] = sd[t] - v;
}

__global__ void k_rowptr(const int* __restrict__ incl, const int* __restrict__ deg,
                         const int* __restrict__ boff, int* __restrict__ row_ptr,
                         int n, int total) {
    int i = blockIdx.x * blockDim.x + threadIdx.x;
    if (i < n) row_ptr[i] = incl[i] - deg[i] + boff[i >> 8];
    if (i == 0) row_ptr[n] = total;
}

__global__ void k_scatter(const int* __restrict__ ei, int E, int E2,
                          const int* __restrict__ row_ptr, int* __restrict__ cursor,
                          int* __restrict__ csr_src) {
    int e = blockIdx.x * blockDim.x + threadIdx.x;
    if (e >= E2) return;
    int se, de;
    if (e < E) { se = ei[e]; de = ei[E + e]; }
    else       { se = e - E; de = se; }
    int pos = atomicAdd(&cursor[de], 1);
    csr_src[row_ptr[de] + pos] = se;
}

// ---- aggregation: wave per node; lane=(e2,c); 16 edges in flight; f16x8 ----
__global__ __launch_bounds__(256) void k_aggregate(const _Float16* __restrict__ hmat,
        const int* __restrict__ row_ptr, const int* __restrict__ csr_src,
        const float* __restrict__ alpha_src, const float* __restrict__ alpha_dst,
        const float* __restrict__ bias, float* __restrict__ outf,
        _Float16* __restrict__ outx, int relu, int nrows) {
    int node = (blockIdx.x * 256 + threadIdx.x) >> 6;
    if (node >= nrows) return;
    int lane = threadIdx.x & 63;
    int e2 = lane >> 5;            // edge-slot half (0/1)
    int c  = lane & 31;            // channel octet: channels c*8..c*8+7
    int head = c >> 3;
    int st = row_ptr[node], en = row_ptr[node + 1];
    int deg = en - st;
    float a_d = alpha_dst[node * 4 + head];
    float acc[8] = {};
    float ssum = 0.f;
    for (int b = 0; b < deg; b += 16) {
        int sn[8];
        #pragma unroll
        for (int j = 0; j < 8; ++j) {
            int e = b + e2 * 8 + j;
            int li = st + (e < deg ? e : deg - 1);
            sn[j] = csr_src[li];
        }
        f16x8 hv[8];
        #pragma unroll
        for (int j = 0; j < 8; ++j)
            hv[j] = *(const f16x8*)&hmat[(size_t)sn[j] * D + c * 8];
        float as[8];
        #pragma unroll
        for (int j = 0; j < 8; ++j) as[j] = alpha_src[sn[j] * 4 + head];
        #pragma unroll
        for (int j = 0; j < 8; ++j) {
            int e = b + e2 * 8 + j;
            float a = as[j] + a_d;
            a = a > 0.f ? a : NEG_SLOPE * a;
            float ex = (e < deg) ? __expf(a) : 0.f;
            ssum += ex;
            #pragma unroll
            for (int k = 0; k < 8; ++k) acc[k] += ex * (float)hv[j][k];
        }
    }
    ssum += __shfl_xor(ssum, 32);
    #pragma unroll
    for (int k = 0; k < 8; ++k) acc[k] += __shfl_xor(acc[k], 32);
    if (e2 == 0) {
        float sinv = 1.f / (ssum + 1e-16f);
        float4 b0 = *(const float4*)&bias[c * 8];
        float4 b1 = *(const float4*)&bias[c * 8 + 4];
        float o[8];
        o[0] = acc[0] * sinv + b0.x; o[1] = acc[1] * sinv + b0.y;
        o[2] = acc[2] * sinv + b0.z; o[3] = acc[3] * sinv + b0.w;
        o[4] = acc[4] * sinv + b1.x; o[5] = acc[5] * sinv + b1.y;
        o[6] = acc[6] * sinv + b1.z; o[7] = acc[7] * sinv + b1.w;
        if (relu) {
            #pragma unroll
            for (int k = 0; k < 8; ++k) o[k] = fmaxf(o[k], 0.f);
        }
        if (outx) {
            f16x8 o8 = {(_Float16)o[0], (_Float16)o[1], (_Float16)o[2], (_Float16)o[3],
                        (_Float16)o[4], (_Float16)o[5], (_Float16)o[6], (_Float16)o[7]};
            *(f16x8*)&outx[(size_t)node * D + c * 8] = o8;
        } else {
            *(float4*)&outf[(size_t)node * D + c * 8] =
                make_float4(o[0], o[1], o[2], o[3]);
            *(float4*)&outf[(size_t)node * D + c * 8 + 4] =
                make_float4(o[4], o[5], o[6], o[7]);
        }
    }
}

extern "C" void kernel_launch(void* const* d_in, const int* in_sizes, int n_in,
                              void* d_out, int out_size, void* d_ws, size_t ws_size,
                              hipStream_t stream) {
    const float* x = (const float*)d_in[0];
    const int* ei = (const int*)d_in[1];
    const int N  = in_sizes[0] / 128;   // 50000
    const int E  = in_sizes[1] / 2;     // 400000
    const int E2 = E + N;               // + self loops

    char* wsp = (char*)d_ws;
    size_t off = 0;
    auto alloc = [&](size_t bytes) -> void* {
        void* p = wsp + off;
        off += (bytes + 255) & ~(size_t)255;
        return p;
    };
    _Float16* bufH  = (_Float16*)alloc((size_t)N * D * 2);     // 25.6 MB
    _Float16* xf16  = (_Float16*)alloc((size_t)N * D * 2);     // 25.6 MB
    _Float16* wfrag = (_Float16*)alloc((size_t)(128 * 256 + 4 * 256 * 256) * 2);
    float* alpha_src = (float*)alloc((size_t)N * H * 4);
    float* alpha_dst = (float*)alloc((size_t)N * H * 4);
    int*   deg       = (int*)alloc((size_t)N * 4);
    int*   incl      = (int*)alloc((size_t)N * 4);
    int*   bsum      = (int*)alloc(256 * 4);
    int*   row_ptr   = (int*)alloc((size_t)(N + 1) * 4);
    int*   cursor    = (int*)alloc((size_t)N * 4);
    int*   csr_src   = (int*)alloc((size_t)E2 * 4);
    (void)ws_size;

    hipMemsetAsync(deg, 0, (size_t)N * 4, stream);
    hipMemsetAsync(cursor, 0, (size_t)N * 4, stream);

    // convert x; reorder W into fragment layout
    int nx4 = N * 128 / 4;
    k_cvt<<<(nx4 + 255) / 256, 256, 0, stream>>>(x, xf16, nx4);
    k_cvt_wfrag<128><<<(16 * 4 * 64 + 255) / 256, 256, 0, stream>>>(
        (const float*)d_in[2], wfrag);
    for (int l = 1; l < 5; ++l)
        k_cvt_wfrag<256><<<(16 * 8 * 64 + 255) / 256, 256, 0, stream>>>(
            (const float*)d_in[2 + 4 * l],
            wfrag + 128 * 256 + (size_t)(l - 1) * 256 * 256);

    // CSR by dst
    int egrid = (E2 + 255) / 256;
    k_deg<<<egrid, 256, 0, stream>>>(ei, E, E2, deg);
    int nb = (N + 255) / 256;
    k_scan_block<<<nb, 256, 0, stream>>>(deg, incl, bsum, N);
    k_scan_bsum<<<1, 256, 0, stream>>>(bsum, nb);
    k_rowptr<<<nb, 256, 0, stream>>>(incl, deg, bsum, row_ptr, N, E2);
    k_scatter<<<egrid, 256, 0, stream>>>(ei, E, E2, row_ptr, cursor, csr_src);

    dim3 ggrid((N + 63) / 64, 2);
    int agrid = (N + 3) / 4;
    for (int l = 0; l < 5; ++l) {
        const float* as_ = (const float*)d_in[3 + 4 * l];
        const float* ad_ = (const float*)d_in[4 + 4 * l];
        const float* bs_ = (const float*)d_in[5 + 4 * l];
        const _Float16* wl = (l == 0) ? wfrag
                           : wfrag + 128 * 256 + (size_t)(l - 1) * 256 * 256;

        if (l == 0)
            k_gemm_mfma<128><<<ggrid, 256, 0, stream>>>(xf16, wl, as_, ad_,
                                                        bufH, alpha_src, alpha_dst, N);
        else
            k_gemm_mfma<256><<<ggrid, 256, 0, stream>>>(xf16, wl, as_, ad_,
                                                        bufH, alpha_src, alpha_dst, N);

        int last = (l == 4);
        k_aggregate<<<agrid, 256, 0, stream>>>(bufH, row_ptr, csr_src,
                                               alpha_src, alpha_dst, bs_,
                                               last ? (float*)d_out : nullptr,
                                               last ? nullptr : xf16,
                                               last ? 0 : 1, N);
    }
}

// Round 13
// 402.577 us; speedup vs baseline: 1.3338x; 1.0518x over previous
//
#include <hip/hip_runtime.h>
#include <hip/hip_bf16.h>

#define H 4
#define D 256
#define NEG_SLOPE 0.2f

typedef __attribute__((ext_vector_type(8))) _Float16 f16x8;
typedef __attribute__((ext_vector_type(4))) _Float16 f16x4;
typedef __attribute__((ext_vector_type(4))) float f32x4;

// ---------------- f32 -> f16 convert (x) ----------------
__global__ void k_cvt(const float* __restrict__ in, _Float16* __restrict__ out, int n4) {
    int i = blockIdx.x * blockDim.x + threadIdx.x;
    if (i >= n4) return;
    float4 v = ((const float4*)in)[i];
    f16x4 o = {(_Float16)v.x, (_Float16)v.y, (_Float16)v.z, (_Float16)v.w};
    *(f16x4*)&out[(size_t)i * 4] = o;
}

// ---- W -> fp16 in MFMA fragment order ----
template<int K>
__device__ __forceinline__ void cvt_wfrag_one(const float* __restrict__ W,
                                              _Float16* __restrict__ wfrag, int idx) {
    const int NKS = K / 32;
    if (idx >= 16 * NKS * 64) return;
    int l  = idx & 63;
    int ks = (idx >> 6) % NKS;
    int c16 = idx / (NKS * 64);
    int col = c16 * 16 + (l & 15);
    int k0  = ks * 32 + (l >> 4) * 8;
    const float* src = &W[(size_t)col * K + k0];
    float4 v0 = *(const float4*)src;
    float4 v1 = *(const float4*)(src + 4);
    f16x8 o = {(_Float16)v0.x, (_Float16)v0.y, (_Float16)v0.z, (_Float16)v0.w,
               (_Float16)v1.x, (_Float16)v1.y, (_Float16)v1.z, (_Float16)v1.w};
    *(f16x8*)&wfrag[(size_t)idx * 8] = o;
}

__global__ void k_cvt_wfrag0(const float* __restrict__ W, _Float16* __restrict__ wfrag) {
    cvt_wfrag_one<128>(W, wfrag, blockIdx.x * blockDim.x + threadIdx.x);
}

// layers 1-4 in one launch: blockIdx.y selects layer
__global__ void k_cvt_wfrag_all(const float* __restrict__ w1, const float* __restrict__ w2,
                                const float* __restrict__ w3, const float* __restrict__ w4,
                                _Float16* __restrict__ wfrag) {
    const float* ws[4] = {w1, w2, w3, w4};
    int l = blockIdx.y;
    cvt_wfrag_one<256>(ws[l], wfrag + 128 * 256 + (size_t)l * 256 * 256,
                       blockIdx.x * blockDim.x + threadIdx.x);
}

// ---- MFMA GEMM v4: W-frag in LDS (staged once), x direct, zero K-loop barriers ----
template<int K>
__global__ __launch_bounds__(256) void k_gemm_mfma(
        const _Float16* __restrict__ xf, const _Float16* __restrict__ wfrag,
        const float* __restrict__ att_src, const float* __restrict__ att_dst,
        _Float16* __restrict__ hmat, float* __restrict__ alpha_src,
        float* __restrict__ alpha_dst, int nrows) {
    const int NKS = K / 32;
    __shared__ _Float16 sw[8 * NKS * 64 * 8];
    int t = threadIdx.x;
    int w = t >> 6, l = t & 63;
    int r = l & 15, q = l >> 4;
    int row0  = blockIdx.x * 64;
    int split = blockIdx.y;

    {
        const uint4* wsrc = (const uint4*)(wfrag + (size_t)split * 8 * NKS * 64 * 8);
        uint4* wdst = (uint4*)sw;
        const int nchunk = 8 * NKS * 64;
        #pragma unroll
        for (int i = 0; i < nchunk / 256; ++i)
            wdst[i * 256 + t] = wsrc[i * 256 + t];
    }

    int gr_a = row0 + w * 16 + r;
    bool aok = (gr_a < nrows);
    f16x8 a[NKS];
    #pragma unroll
    for (int ks = 0; ks < NKS; ++ks) {
        if (aok) a[ks] = *(const f16x8*)&xf[(size_t)gr_a * K + ks * 32 + q * 8];
        else     a[ks] = (f16x8){0, 0, 0, 0, 0, 0, 0, 0};
    }

    __syncthreads();

    f32x4 acc[8];
    #pragma unroll
    for (int cf = 0; cf < 8; ++cf) acc[cf] = (f32x4){0.f, 0.f, 0.f, 0.f};
    #pragma unroll
    for (int cf = 0; cf < 8; ++cf) {
        f16x8 b[NKS];
        #pragma unroll
        for (int ks = 0; ks < NKS; ++ks)
            b[ks] = *(f16x8*)&sw[(size_t)((cf * NKS + ks) * 64 + l) * 8];
        #pragma unroll
        for (int ks = 0; ks < NKS; ++ks)
            acc[cf] = __builtin_amdgcn_mfma_f32_16x16x32_f16(a[ks], b[ks], acc[cf], 0, 0, 0);
    }

    #pragma unroll
    for (int cf = 0; cf < 8; ++cf) {
        #pragma unroll
        for (int i = 0; i < 4; ++i) {
            int gr = row0 + w * 16 + q * 4 + i;
            if (gr < nrows)
                hmat[(size_t)gr * D + split * 128 + cf * 16 + r] = (_Float16)acc[cf][i];
        }
    }
    float asv[8], adv[8];
    #pragma unroll
    for (int cf = 0; cf < 8; ++cf) {
        asv[cf] = att_src[split * 128 + cf * 16 + r];
        adv[cf] = att_dst[split * 128 + cf * 16 + r];
    }
    #pragma unroll
    for (int i = 0; i < 4; ++i) {
        #pragma unroll
        for (int hh = 0; hh < 2; ++hh) {
            float ps = 0.f, pd = 0.f;
            #pragma unroll
            for (int j = 0; j < 4; ++j) {
                int cf = hh * 4 + j;
                ps += acc[cf][i] * asv[cf];
                pd += acc[cf][i] * adv[cf];
            }
            #pragma unroll
            for (int m = 1; m < 16; m <<= 1) {
                ps += __shfl_xor(ps, m);
                pd += __shfl_xor(pd, m);
            }
            int gr = row0 + w * 16 + q * 4 + i;
            if (r == 0 && gr < nrows) {
                alpha_src[gr * 4 + split * 2 + hh] = ps;
                alpha_dst[gr * 4 + split * 2 + hh] = pd;
            }
        }
    }
}

// ---------------- CSR build (graph constant across layers) ----------------
__global__ void k_deg(const int* __restrict__ ei, int E, int E2, int* __restrict__ deg) {
    int e = blockIdx.x * blockDim.x + threadIdx.x;
    if (e >= E2) return;
    int de = (e < E) ? ei[E + e] : (e - E);
    atomicAdd(&deg[de], 1);
}

__global__ void k_scan_block(const int* __restrict__ deg, int* __restrict__ incl,
                             int* __restrict__ bsum, int n) {
    __shared__ int sd[256];
    int t = threadIdx.x;
    int i = blockIdx.x * 256 + t;
    int v = (i < n) ? deg[i] : 0;
    sd[t] = v;
    __syncthreads();
    for (int off = 1; off < 256; off <<= 1) {
        int add = (t >= off) ? sd[t - off] : 0;
        __syncthreads();
        sd[t] += add;
        __syncthreads();
    }
    if (i < n) incl[i] = sd[t];
    if (t == 255) bsum[blockIdx.x] = sd[255];
}

__global__ void k_scan_bsum(int* __restrict__ bsum, int nb) {
    __shared__ int sd[256];
    int t = threadIdx.x;
    int v = (t < nb) ? bsum[t] : 0;
    sd[t] = v;
    __syncthreads();
    for (int off = 1; off < 256; off <<= 1) {
        int add = (t >= off) ? sd[t - off] : 0;
        __syncthreads();
        sd[t] += add;
        __syncthreads();
    }
    if (t < nb) bsum[t] = sd[t] - v;
}

__global__ void k_rowptr(const int* __restrict__ incl, const int* __restrict__ deg,
                         const int* __restrict__ boff, int* __restrict__ row_ptr,
                         int n, int total) {
    int i = blockIdx.x * blockDim.x + threadIdx.x;
    if (i < n) row_ptr[i] = incl[i] - deg[i] + boff[i >> 8];
    if (i == 0) row_ptr[n] = total;
}

__global__ void k_scatter(const int* __restrict__ ei, int E, int E2,
                          const int* __restrict__ row_ptr, int* __restrict__ cursor,
                          int* __restrict__ csr_src) {
    int e = blockIdx.x * blockDim.x + threadIdx.x;
    if (e >= E2) return;
    int se, de;
    if (e < E) { se = ei[e]; de = ei[E + e]; }
    else       { se = e - E; de = se; }
    int pos = atomicAdd(&cursor[de], 1);
    csr_src[row_ptr[de] + pos] = se;
}

// ---- aggregation v5: 2 nodes per wave, 32 lanes/node, NO cross-lane reduce ----
__global__ __launch_bounds__(256) void k_aggregate(const _Float16* __restrict__ hmat,
        const int* __restrict__ row_ptr, const int* __restrict__ csr_src,
        const float* __restrict__ alpha_src, const float* __restrict__ alpha_dst,
        const float* __restrict__ bias, float* __restrict__ outf,
        _Float16* __restrict__ outx, int relu, int nrows) {
    int wid  = (blockIdx.x * 256 + threadIdx.x) >> 6;
    int lane = threadIdx.x & 63;
    int node = wid * 2 + (lane >> 5);      // 2 nodes per wave
    if (node >= nrows) return;
    int c    = lane & 31;                  // channel octet: channels c*8..c*8+7
    int head = c >> 3;
    int st = row_ptr[node], en = row_ptr[node + 1];
    int deg = en - st;
    float a_d = alpha_dst[node * 4 + head];
    float acc[8] = {};
    float ssum = 0.f;
    for (int b = 0; b < deg; b += 8) {
        int sn[8];
        #pragma unroll
        for (int j = 0; j < 8; ++j) {
            int e = b + j;
            int li = st + (e < deg ? e : deg - 1);
            sn[j] = csr_src[li];
        }
        f16x8 hv[8];
        #pragma unroll
        for (int j = 0; j < 8; ++j)
            hv[j] = *(const f16x8*)&hmat[(size_t)sn[j] * D + c * 8];
        float as[8];
        #pragma unroll
        for (int j = 0; j < 8; ++j) as[j] = alpha_src[sn[j] * 4 + head];
        #pragma unroll
        for (int j = 0; j < 8; ++j) {
            float a = as[j] + a_d;
            a = a > 0.f ? a : NEG_SLOPE * a;
            float ex = (b + j < deg) ? __expf(a) : 0.f;
            ssum += ex;
            #pragma unroll
            for (int k = 0; k < 8; ++k) acc[k] += ex * (float)hv[j][k];
        }
    }
    float sinv = 1.f / (ssum + 1e-16f);
    float4 b0 = *(const float4*)&bias[c * 8];
    float4 b1 = *(const float4*)&bias[c * 8 + 4];
    float o[8];
    o[0] = acc[0] * sinv + b0.x; o[1] = acc[1] * sinv + b0.y;
    o[2] = acc[2] * sinv + b0.z; o[3] = acc[3] * sinv + b0.w;
    o[4] = acc[4] * sinv + b1.x; o[5] = acc[5] * sinv + b1.y;
    o[6] = acc[6] * sinv + b1.z; o[7] = acc[7] * sinv + b1.w;
    if (relu) {
        #pragma unroll
        for (int k = 0; k < 8; ++k) o[k] = fmaxf(o[k], 0.f);
    }
    if (outx) {
        f16x8 o8 = {(_Float16)o[0], (_Float16)o[1], (_Float16)o[2], (_Float16)o[3],
                    (_Float16)o[4], (_Float16)o[5], (_Float16)o[6], (_Float16)o[7]};
        *(f16x8*)&outx[(size_t)node * D + c * 8] = o8;
    } else {
        *(float4*)&outf[(size_t)node * D + c * 8] =
            make_float4(o[0], o[1], o[2], o[3]);
        *(float4*)&outf[(size_t)node * D + c * 8 + 4] =
            make_float4(o[4], o[5], o[6], o[7]);
    }
}

extern "C" void kernel_launch(void* const* d_in, const int* in_sizes, int n_in,
                              void* d_out, int out_size, void* d_ws, size_t ws_size,
                              hipStream_t stream) {
    const float* x = (const float*)d_in[0];
    const int* ei = (const int*)d_in[1];
    const int N  = in_sizes[0] / 128;   // 50000
    const int E  = in_sizes[1] / 2;     // 400000
    const int E2 = E + N;               // + self loops

    char* wsp = (char*)d_ws;
    size_t off = 0;
    auto alloc = [&](size_t bytes) -> void* {
        void* p = wsp + off;
        off += (bytes + 255) & ~(size_t)255;
        return p;
    };
    _Float16* bufH  = (_Float16*)alloc((size_t)N * D * 2);     // 25.6 MB
    _Float16* xf16  = (_Float16*)alloc((size_t)N * D * 2);     // 25.6 MB
    _Float16* wfrag = (_Float16*)alloc((size_t)(128 * 256 + 4 * 256 * 256) * 2);
    float* alpha_src = (float*)alloc((size_t)N * H * 4);
    float* alpha_dst = (float*)alloc((size_t)N * H * 4);
    int*   deg       = (int*)alloc((size_t)N * 4);
    int*   incl      = (int*)alloc((size_t)N * 4);
    int*   bsum      = (int*)alloc(256 * 4);
    int*   row_ptr   = (int*)alloc((size_t)(N + 1) * 4);
    int*   cursor    = (int*)alloc((size_t)N * 4);
    int*   csr_src   = (int*)alloc((size_t)E2 * 4);
    (void)ws_size;

    hipMemsetAsync(deg, 0, (size_t)N * 4, stream);
    hipMemsetAsync(cursor, 0, (size_t)N * 4, stream);

    // convert x; reorder W into fragment layout (layer 0 + merged layers 1-4)
    int nx4 = N * 128 / 4;
    k_cvt<<<(nx4 + 255) / 256, 256, 0, stream>>>(x, xf16, nx4);
    k_cvt_wfrag0<<<(16 * 4 * 64 + 255) / 256, 256, 0, stream>>>(
        (const float*)d_in[2], wfrag);
    dim3 wg((16 * 8 * 64 + 255) / 256, 4);
    k_cvt_wfrag_all<<<wg, 256, 0, stream>>>(
        (const float*)d_in[6], (const float*)d_in[10],
        (const float*)d_in[14], (const float*)d_in[18], wfrag);

    // CSR by dst
    int egrid = (E2 + 255) / 256;
    k_deg<<<egrid, 256, 0, stream>>>(ei, E, E2, deg);
    int nb = (N + 255) / 256;
    k_scan_block<<<nb, 256, 0, stream>>>(deg, incl, bsum, N);
    k_scan_bsum<<<1, 256, 0, stream>>>(bsum, nb);
    k_rowptr<<<nb, 256, 0, stream>>>(incl, deg, bsum, row_ptr, N, E2);
    k_scatter<<<egrid, 256, 0, stream>>>(ei, E, E2, row_ptr, cursor, csr_src);

    dim3 ggrid((N + 63) / 64, 2);
    int agrid = (N + 7) / 8;            // 4 waves x 2 nodes per block
    for (int l = 0; l < 5; ++l) {
        const float* as_ = (const float*)d_in[3 + 4 * l];
        const float* ad_ = (const float*)d_in[4 + 4 * l];
        const float* bs_ = (const float*)d_in[5 + 4 * l];
        const _Float16* wl = (l == 0) ? wfrag
                           : wfrag + 128 * 256 + (size_t)(l - 1) * 256 * 256;

        if (l == 0)
            k_gemm_mfma<128><<<ggrid, 256, 0, stream>>>(xf16, wl, as_, ad_,
                                                        bufH, alpha_src, alpha_dst, N);
        else
            k_gemm_mfma<256><<<ggrid, 256, 0, stream>>>(xf16, wl, as_, ad_,
                                                        bufH, alpha_src, alpha_dst, N);

        int last = (l == 4);
        k_aggregate<<<agrid, 256, 0, stream>>>(bufH, row_ptr, csr_src,
                                               alpha_src, alpha_dst, bs_,
                                               last ? (float*)d_out : nullptr,
                                               last ? nullptr : xf16,
                                               last ? 0 : 1, N);
    }
}

// Round 14
// 392.266 us; speedup vs baseline: 1.3689x; 1.0263x over previous
//
#include <hip/hip_runtime.h>
#include <hip/hip_bf16.h>

#define H 4
#define D 256
#define NEG_SLOPE 0.2f

typedef __attribute__((ext_vector_type(8))) _Float16 f16x8;
typedef __attribute__((ext_vector_type(4))) _Float16 f16x4;
typedef __attribute__((ext_vector_type(4))) float f32x4;

// ---- W -> fp16 in MFMA fragment order ----
template<int K>
__device__ __forceinline__ void cvt_wfrag_one(const float* __restrict__ W,
                                              _Float16* __restrict__ wfrag, int idx) {
    const int NKS = K / 32;
    if (idx >= 16 * NKS * 64) return;
    int l  = idx & 63;
    int ks = (idx >> 6) % NKS;
    int c16 = idx / (NKS * 64);
    int col = c16 * 16 + (l & 15);
    int k0  = ks * 32 + (l >> 4) * 8;
    const float* src = &W[(size_t)col * K + k0];
    float4 v0 = *(const float4*)src;
    float4 v1 = *(const float4*)(src + 4);
    f16x8 o = {(_Float16)v0.x, (_Float16)v0.y, (_Float16)v0.z, (_Float16)v0.w,
               (_Float16)v1.x, (_Float16)v1.y, (_Float16)v1.z, (_Float16)v1.w};
    *(f16x8*)&wfrag[(size_t)idx * 8] = o;
}

__global__ void k_cvt_wfrag0(const float* __restrict__ W, _Float16* __restrict__ wfrag) {
    cvt_wfrag_one<128>(W, wfrag, blockIdx.x * blockDim.x + threadIdx.x);
}

__global__ void k_cvt_wfrag_all(const float* __restrict__ w1, const float* __restrict__ w2,
                                const float* __restrict__ w3, const float* __restrict__ w4,
                                _Float16* __restrict__ wfrag) {
    const float* ws[4] = {w1, w2, w3, w4};
    int l = blockIdx.y;
    cvt_wfrag_one<256>(ws[l], wfrag + 128 * 256 + (size_t)l * 256 * 256,
                       blockIdx.x * blockDim.x + threadIdx.x);
}

// ---- MFMA GEMM v4.1: W-frag LDS (once), x direct (f32 or f16), linearized grid ----
// grid = ceil(N/64)*2 blocks; row-chunk = bid>>1, split = bid&1 (adjacent -> same
// XCD -> x reread is L2-hit). 4 waves; wave = 16 rows x 128 cols.
template<int K, bool F32X>
__global__ __launch_bounds__(256) void k_gemm_mfma(
        const void* __restrict__ xin, const _Float16* __restrict__ wfrag,
        const float* __restrict__ att_src, const float* __restrict__ att_dst,
        _Float16* __restrict__ hmat, float* __restrict__ alpha_src,
        float* __restrict__ alpha_dst, int nrows) {
    const int NKS = K / 32;
    __shared__ _Float16 sw[8 * NKS * 64 * 8];
    int t = threadIdx.x;
    int w = t >> 6, l = t & 63;
    int r = l & 15, q = l >> 4;
    int row0  = (blockIdx.x >> 1) * 64;
    int split = blockIdx.x & 1;

    {
        const uint4* wsrc = (const uint4*)(wfrag + (size_t)split * 8 * NKS * 64 * 8);
        uint4* wdst = (uint4*)sw;
        const int nchunk = 8 * NKS * 64;
        #pragma unroll
        for (int i = 0; i < nchunk / 256; ++i)
            wdst[i * 256 + t] = wsrc[i * 256 + t];
    }

    int gr_a = row0 + w * 16 + r;
    bool aok = (gr_a < nrows);
    f16x8 a[NKS];
    #pragma unroll
    for (int ks = 0; ks < NKS; ++ks) {
        if (aok) {
            if constexpr (F32X) {
                const float* xs = (const float*)xin + (size_t)gr_a * K + ks * 32 + q * 8;
                float4 v0 = *(const float4*)xs;
                float4 v1 = *(const float4*)(xs + 4);
                a[ks] = (f16x8){(_Float16)v0.x, (_Float16)v0.y, (_Float16)v0.z,
                                (_Float16)v0.w, (_Float16)v1.x, (_Float16)v1.y,
                                (_Float16)v1.z, (_Float16)v1.w};
            } else {
                a[ks] = *(const f16x8*)((const _Float16*)xin + (size_t)gr_a * K + ks * 32 + q * 8);
            }
        } else {
            a[ks] = (f16x8){0, 0, 0, 0, 0, 0, 0, 0};
        }
    }

    __syncthreads();

    f32x4 acc[8];
    #pragma unroll
    for (int cf = 0; cf < 8; ++cf) acc[cf] = (f32x4){0.f, 0.f, 0.f, 0.f};
    #pragma unroll
    for (int cf = 0; cf < 8; ++cf) {
        f16x8 b[NKS];
        #pragma unroll
        for (int ks = 0; ks < NKS; ++ks)
            b[ks] = *(f16x8*)&sw[(size_t)((cf * NKS + ks) * 64 + l) * 8];
        #pragma unroll
        for (int ks = 0; ks < NKS; ++ks)
            acc[cf] = __builtin_amdgcn_mfma_f32_16x16x32_f16(a[ks], b[ks], acc[cf], 0, 0, 0);
    }

    #pragma unroll
    for (int cf = 0; cf < 8; ++cf) {
        #pragma unroll
        for (int i = 0; i < 4; ++i) {
            int gr = row0 + w * 16 + q * 4 + i;
            if (gr < nrows)
                hmat[(size_t)gr * D + split * 128 + cf * 16 + r] = (_Float16)acc[cf][i];
        }
    }
    float asv[8], adv[8];
    #pragma unroll
    for (int cf = 0; cf < 8; ++cf) {
        asv[cf] = att_src[split * 128 + cf * 16 + r];
        adv[cf] = att_dst[split * 128 + cf * 16 + r];
    }
    #pragma unroll
    for (int i = 0; i < 4; ++i) {
        #pragma unroll
        for (int hh = 0; hh < 2; ++hh) {
            float ps = 0.f, pd = 0.f;
            #pragma unroll
            for (int j = 0; j < 4; ++j) {
                int cf = hh * 4 + j;
                ps += acc[cf][i] * asv[cf];
                pd += acc[cf][i] * adv[cf];
            }
            #pragma unroll
            for (int m = 1; m < 16; m <<= 1) {
                ps += __shfl_xor(ps, m);
                pd += __shfl_xor(pd, m);
            }
            int gr = row0 + w * 16 + q * 4 + i;
            if (r == 0 && gr < nrows) {
                alpha_src[gr * 4 + split * 2 + hh] = ps;
                alpha_dst[gr * 4 + split * 2 + hh] = pd;
            }
        }
    }
}

// ---------------- CSR build (graph constant across layers) ----------------
__global__ void k_deg(const int* __restrict__ ei, int E, int E2, int* __restrict__ deg) {
    int e = blockIdx.x * blockDim.x + threadIdx.x;
    if (e >= E2) return;
    int de = (e < E) ? ei[E + e] : (e - E);
    atomicAdd(&deg[de], 1);
}

__global__ void k_scan_block(const int* __restrict__ deg, int* __restrict__ incl,
                             int* __restrict__ bsum, int n) {
    __shared__ int sd[256];
    int t = threadIdx.x;
    int i = blockIdx.x * 256 + t;
    int v = (i < n) ? deg[i] : 0;
    sd[t] = v;
    __syncthreads();
    for (int off = 1; off < 256; off <<= 1) {
        int add = (t >= off) ? sd[t - off] : 0;
        __syncthreads();
        sd[t] += add;
        __syncthreads();
    }
    if (i < n) incl[i] = sd[t];
    if (t == 255) bsum[blockIdx.x] = sd[255];
}

__global__ void k_scan_bsum(int* __restrict__ bsum, int nb) {
    __shared__ int sd[256];
    int t = threadIdx.x;
    int v = (t < nb) ? bsum[t] : 0;
    sd[t] = v;
    __syncthreads();
    for (int off = 1; off < 256; off <<= 1) {
        int add = (t >= off) ? sd[t - off] : 0;
        __syncthreads();
        sd[t] += add;
        __syncthreads();
    }
    if (t < nb) bsum[t] = sd[t] - v;
}

__global__ void k_rowptr(const int* __restrict__ incl, const int* __restrict__ deg,
                         const int* __restrict__ boff, int* __restrict__ row_ptr,
                         int n, int total) {
    int i = blockIdx.x * blockDim.x + threadIdx.x;
    if (i < n) row_ptr[i] = incl[i] - deg[i] + boff[i >> 8];
    if (i == 0) row_ptr[n] = total;
}

__global__ void k_scatter(const int* __restrict__ ei, int E, int E2,
                          const int* __restrict__ row_ptr, int* __restrict__ cursor,
                          int* __restrict__ csr_src) {
    int e = blockIdx.x * blockDim.x + threadIdx.x;
    if (e >= E2) return;
    int se, de;
    if (e < E) { se = ei[e]; de = ei[E + e]; }
    else       { se = e - E; de = se; }
    int pos = atomicAdd(&cursor[de], 1);
    csr_src[row_ptr[de] + pos] = se;
}

// ---- aggregation v5.1: 2 nodes/wave, 32 lanes/node, idx-prefetch pipeline ----
__global__ __launch_bounds__(256) void k_aggregate(const _Float16* __restrict__ hmat,
        const int* __restrict__ row_ptr, const int* __restrict__ csr_src,
        const float* __restrict__ alpha_src, const float* __restrict__ alpha_dst,
        const float* __restrict__ bias, float* __restrict__ outf,
        _Float16* __restrict__ outx, int relu, int nrows) {
    int wid  = (blockIdx.x * 256 + threadIdx.x) >> 6;
    int lane = threadIdx.x & 63;
    int node = wid * 2 + (lane >> 5);      // 2 nodes per wave
    if (node >= nrows) return;
    int c    = lane & 31;                  // channel octet: channels c*8..c*8+7
    int head = c >> 3;
    int st = row_ptr[node], en = row_ptr[node + 1];
    int deg = en - st;
    int nbatch = (deg + 7) >> 3;
    float a_d = alpha_dst[node * 4 + head];
    float acc[8] = {};
    float ssum = 0.f;
    // prologue: batch-0 indices
    int sn[8];
    #pragma unroll
    for (int j = 0; j < 8; ++j) {
        int li = st + (j < deg ? j : deg - 1);
        sn[j] = csr_src[li];
    }
    for (int b = 0; b < nbatch; ++b) {
        f16x8 hv[8];
        #pragma unroll
        for (int j = 0; j < 8; ++j)
            hv[j] = *(const f16x8*)&hmat[(size_t)sn[j] * D + c * 8];
        float as[8];
        #pragma unroll
        for (int j = 0; j < 8; ++j) as[j] = alpha_src[sn[j] * 4 + head];
        // prefetch next batch's indices (overlaps the gathers above)
        int sn2[8];
        if (b + 1 < nbatch) {
            #pragma unroll
            for (int j = 0; j < 8; ++j) {
                int e = (b + 1) * 8 + j;
                int li = st + (e < deg ? e : deg - 1);
                sn2[j] = csr_src[li];
            }
        }
        #pragma unroll
        for (int j = 0; j < 8; ++j) {
            float a = as[j] + a_d;
            a = a > 0.f ? a : NEG_SLOPE * a;
            float ex = (b * 8 + j < deg) ? __expf(a) : 0.f;
            ssum += ex;
            #pragma unroll
            for (int k = 0; k < 8; ++k) acc[k] += ex * (float)hv[j][k];
        }
        #pragma unroll
        for (int j = 0; j < 8; ++j) sn[j] = sn2[j];
    }
    float sinv = 1.f / (ssum + 1e-16f);
    float4 b0 = *(const float4*)&bias[c * 8];
    float4 b1 = *(const float4*)&bias[c * 8 + 4];
    float o[8];
    o[0] = acc[0] * sinv + b0.x; o[1] = acc[1] * sinv + b0.y;
    o[2] = acc[2] * sinv + b0.z; o[3] = acc[3] * sinv + b0.w;
    o[4] = acc[4] * sinv + b1.x; o[5] = acc[5] * sinv + b1.y;
    o[6] = acc[6] * sinv + b1.z; o[7] = acc[7] * sinv + b1.w;
    if (relu) {
        #pragma unroll
        for (int k = 0; k < 8; ++k) o[k] = fmaxf(o[k], 0.f);
    }
    if (outx) {
        f16x8 o8 = {(_Float16)o[0], (_Float16)o[1], (_Float16)o[2], (_Float16)o[3],
                    (_Float16)o[4], (_Float16)o[5], (_Float16)o[6], (_Float16)o[7]};
        *(f16x8*)&outx[(size_t)node * D + c * 8] = o8;
    } else {
        *(float4*)&outf[(size_t)node * D + c * 8] =
            make_float4(o[0], o[1], o[2], o[3]);
        *(float4*)&outf[(size_t)node * D + c * 8 + 4] =
            make_float4(o[4], o[5], o[6], o[7]);
    }
}

extern "C" void kernel_launch(void* const* d_in, const int* in_sizes, int n_in,
                              void* d_out, int out_size, void* d_ws, size_t ws_size,
                              hipStream_t stream) {
    const float* x = (const float*)d_in[0];
    const int* ei = (const int*)d_in[1];
    const int N  = in_sizes[0] / 128;   // 50000
    const int E  = in_sizes[1] / 2;     // 400000
    const int E2 = E + N;               // + self loops

    char* wsp = (char*)d_ws;
    size_t off = 0;
    auto alloc = [&](size_t bytes) -> void* {
        void* p = wsp + off;
        off += (bytes + 255) & ~(size_t)255;
        return p;
    };
    _Float16* bufH  = (_Float16*)alloc((size_t)N * D * 2);     // 25.6 MB
    _Float16* xf16  = (_Float16*)alloc((size_t)N * D * 2);     // 25.6 MB
    _Float16* wfrag = (_Float16*)alloc((size_t)(128 * 256 + 4 * 256 * 256) * 2);
    float* alpha_src = (float*)alloc((size_t)N * H * 4);
    float* alpha_dst = (float*)alloc((size_t)N * H * 4);
    int*   deg       = (int*)alloc((size_t)N * 4);
    int*   incl      = (int*)alloc((size_t)N * 4);
    int*   bsum      = (int*)alloc(256 * 4);
    int*   row_ptr   = (int*)alloc((size_t)(N + 1) * 4);
    int*   cursor    = (int*)alloc((size_t)N * 4);
    int*   csr_src   = (int*)alloc((size_t)E2 * 4);
    (void)ws_size;

    hipMemsetAsync(deg, 0, (size_t)N * 4, stream);
    hipMemsetAsync(cursor, 0, (size_t)N * 4, stream);

    // W -> fragment layout (layer 0 + merged layers 1-4); x stays f32 for layer 0
    k_cvt_wfrag0<<<(16 * 4 * 64 + 255) / 256, 256, 0, stream>>>(
        (const float*)d_in[2], wfrag);
    dim3 wg((16 * 8 * 64 + 255) / 256, 4);
    k_cvt_wfrag_all<<<wg, 256, 0, stream>>>(
        (const float*)d_in[6], (const float*)d_in[10],
        (const float*)d_in[14], (const float*)d_in[18], wfrag);

    // CSR by dst
    int egrid = (E2 + 255) / 256;
    k_deg<<<egrid, 256, 0, stream>>>(ei, E, E2, deg);
    int nb = (N + 255) / 256;
    k_scan_block<<<nb, 256, 0, stream>>>(deg, incl, bsum, N);
    k_scan_bsum<<<1, 256, 0, stream>>>(bsum, nb);
    k_rowptr<<<nb, 256, 0, stream>>>(incl, deg, bsum, row_ptr, N, E2);
    k_scatter<<<egrid, 256, 0, stream>>>(ei, E, E2, row_ptr, cursor, csr_src);

    int ggrid = ((N + 63) / 64) * 2;    // linearized: split adjacent
    int agrid = (N + 7) / 8;            // 4 waves x 2 nodes per block
    for (int l = 0; l < 5; ++l) {
        const float* as_ = (const float*)d_in[3 + 4 * l];
        const float* ad_ = (const float*)d_in[4 + 4 * l];
        const float* bs_ = (const float*)d_in[5 + 4 * l];
        const _Float16* wl = (l == 0) ? wfrag
                           : wfrag + 128 * 256 + (size_t)(l - 1) * 256 * 256;

        if (l == 0)
            k_gemm_mfma<128, true><<<ggrid, 256, 0, stream>>>(x, wl, as_, ad_,
                                                        bufH, alpha_src, alpha_dst, N);
        else
            k_gemm_mfma<256, false><<<ggrid, 256, 0, stream>>>(xf16, wl, as_, ad_,
                                                        bufH, alpha_src, alpha_dst, N);

        int last = (l == 4);
        k_aggregate<<<agrid, 256, 0, stream>>>(bufH, row_ptr, csr_src,
                                               alpha_src, alpha_dst, bs_,
                                               last ? (float*)d_out : nullptr,
                                               last ? nullptr : xf16,
                                               last ? 0 : 1, N);
    }
}

// Round 15
// 374.867 us; speedup vs baseline: 1.4324x; 1.0464x over previous
//
#include <hip/hip_runtime.h>
#include <hip/hip_bf16.h>

#define H 4
#define D 256
#define NEG_SLOPE 0.2f

typedef __attribute__((ext_vector_type(8))) _Float16 f16x8;
typedef __attribute__((ext_vector_type(4))) _Float16 f16x4;
typedef __attribute__((ext_vector_type(4))) float f32x4;

// ---- W -> fp16 in MFMA fragment order ----
template<int K>
__device__ __forceinline__ void cvt_wfrag_one(const float* __restrict__ W,
                                              _Float16* __restrict__ wfrag, int idx) {
    const int NKS = K / 32;
    if (idx >= 16 * NKS * 64) return;
    int l  = idx & 63;
    int ks = (idx >> 6) % NKS;
    int c16 = idx / (NKS * 64);
    int col = c16 * 16 + (l & 15);
    int k0  = ks * 32 + (l >> 4) * 8;
    const float* src = &W[(size_t)col * K + k0];
    float4 v0 = *(const float4*)src;
    float4 v1 = *(const float4*)(src + 4);
    f16x8 o = {(_Float16)v0.x, (_Float16)v0.y, (_Float16)v0.z, (_Float16)v0.w,
               (_Float16)v1.x, (_Float16)v1.y, (_Float16)v1.z, (_Float16)v1.w};
    *(f16x8*)&wfrag[(size_t)idx * 8] = o;
}

__global__ void k_cvt_wfrag0(const float* __restrict__ W, _Float16* __restrict__ wfrag) {
    cvt_wfrag_one<128>(W, wfrag, blockIdx.x * blockDim.x + threadIdx.x);
}

__global__ void k_cvt_wfrag_all(const float* __restrict__ w1, const float* __restrict__ w2,
                                const float* __restrict__ w3, const float* __restrict__ w4,
                                _Float16* __restrict__ wfrag) {
    const float* ws[4] = {w1, w2, w3, w4};
    int l = blockIdx.y;
    cvt_wfrag_one<256>(ws[l], wfrag + 128 * 256 + (size_t)l * 256 * 256,
                       blockIdx.x * blockDim.x + threadIdx.x);
}

// ---- MFMA GEMM v6: 4-way col split (1 head/block), 32KB LDS, XCD-pinned ----
// bid%8 = XCD (round-robin); all 4 splits of a row-chunk map to the same XCD
// so the x re-reads are L2 hits. Wave = 16 rows x 64 cols, 4 cf accs.
template<int K, bool F32X>
__global__ __launch_bounds__(256) void k_gemm_mfma(
        const void* __restrict__ xin, const _Float16* __restrict__ wfrag,
        const float* __restrict__ att_src, const float* __restrict__ att_dst,
        _Float16* __restrict__ hmat, float* __restrict__ alpha_src,
        float* __restrict__ alpha_dst, int nrows, int nchunk) {
    const int NKS = K / 32;
    __shared__ _Float16 sw[4 * NKS * 64 * 8];          // 32KB (K=256) / 16KB (K=128)
    int t = threadIdx.x;
    int w = t >> 6, l = t & 63;
    int r = l & 15, q = l >> 4;

    // XCD-pinned (chunk, split) decode: chunk%8 == bid%8 for the main range
    int bid = blockIdx.x;
    int nfull = (nchunk >> 3) << 3;
    int dmain = nfull * 4;
    int chunk, split;
    if (bid < dmain) {
        int j = bid >> 3;
        chunk = (bid & 7) + 8 * (j >> 2);
        split = j & 3;
    } else {
        int idx = bid - dmain;
        chunk = nfull + (idx >> 2);
        split = idx & 3;
    }
    int row0 = chunk * 64;

    // stage this split's W fragments (4 col-frags x NKS) -> LDS
    {
        const uint4* wsrc = (const uint4*)(wfrag + (size_t)split * 4 * NKS * 64 * 8);
        uint4* wdst = (uint4*)sw;
        #pragma unroll
        for (int i = 0; i < NKS; ++i)
            wdst[i * 256 + t] = wsrc[i * 256 + t];
    }

    int gr_a = row0 + w * 16 + r;
    bool aok = (gr_a < nrows);
    f16x8 a[NKS];
    #pragma unroll
    for (int ks = 0; ks < NKS; ++ks) {
        if (aok) {
            if constexpr (F32X) {
                const float* xs = (const float*)xin + (size_t)gr_a * K + ks * 32 + q * 8;
                float4 v0 = *(const float4*)xs;
                float4 v1 = *(const float4*)(xs + 4);
                a[ks] = (f16x8){(_Float16)v0.x, (_Float16)v0.y, (_Float16)v0.z,
                                (_Float16)v0.w, (_Float16)v1.x, (_Float16)v1.y,
                                (_Float16)v1.z, (_Float16)v1.w};
            } else {
                a[ks] = *(const f16x8*)((const _Float16*)xin + (size_t)gr_a * K + ks * 32 + q * 8);
            }
        } else {
            a[ks] = (f16x8){0, 0, 0, 0, 0, 0, 0, 0};
        }
    }

    __syncthreads();

    f32x4 acc[4];
    #pragma unroll
    for (int cf = 0; cf < 4; ++cf) acc[cf] = (f32x4){0.f, 0.f, 0.f, 0.f};
    #pragma unroll
    for (int cf = 0; cf < 4; ++cf) {
        f16x8 b[NKS];
        #pragma unroll
        for (int ks = 0; ks < NKS; ++ks)
            b[ks] = *(f16x8*)&sw[(size_t)((cf * NKS + ks) * 64 + l) * 8];
        #pragma unroll
        for (int ks = 0; ks < NKS; ++ks)
            acc[cf] = __builtin_amdgcn_mfma_f32_16x16x32_f16(a[ks], b[ks], acc[cf], 0, 0, 0);
    }

    // store h: col = split*64 + cf*16 + r
    #pragma unroll
    for (int cf = 0; cf < 4; ++cf) {
        #pragma unroll
        for (int i = 0; i < 4; ++i) {
            int gr = row0 + w * 16 + q * 4 + i;
            if (gr < nrows)
                hmat[(size_t)gr * D + split * 64 + cf * 16 + r] = (_Float16)acc[cf][i];
        }
    }
    // fused alpha: this block's 64 cols == head `split`
    float asv[4], adv[4];
    #pragma unroll
    for (int cf = 0; cf < 4; ++cf) {
        asv[cf] = att_src[split * 64 + cf * 16 + r];
        adv[cf] = att_dst[split * 64 + cf * 16 + r];
    }
    #pragma unroll
    for (int i = 0; i < 4; ++i) {
        float ps = 0.f, pd = 0.f;
        #pragma unroll
        for (int cf = 0; cf < 4; ++cf) {
            ps += acc[cf][i] * asv[cf];
            pd += acc[cf][i] * adv[cf];
        }
        #pragma unroll
        for (int m = 1; m < 16; m <<= 1) {
            ps += __shfl_xor(ps, m);
            pd += __shfl_xor(pd, m);
        }
        int gr = row0 + w * 16 + q * 4 + i;
        if (r == 0 && gr < nrows) {
            alpha_src[gr * 4 + split] = ps;
            alpha_dst[gr * 4 + split] = pd;
        }
    }
}

// ---------------- CSR build (graph constant across layers) ----------------
__global__ void k_deg(const int* __restrict__ ei, int E, int E2, int* __restrict__ deg) {
    int e = blockIdx.x * blockDim.x + threadIdx.x;
    if (e >= E2) return;
    int de = (e < E) ? ei[E + e] : (e - E);
    atomicAdd(&deg[de], 1);
}

__global__ void k_scan_block(const int* __restrict__ deg, int* __restrict__ incl,
                             int* __restrict__ bsum, int n) {
    __shared__ int sd[256];
    int t = threadIdx.x;
    int i = blockIdx.x * 256 + t;
    int v = (i < n) ? deg[i] : 0;
    sd[t] = v;
    __syncthreads();
    for (int off = 1; off < 256; off <<= 1) {
        int add = (t >= off) ? sd[t - off] : 0;
        __syncthreads();
        sd[t] += add;
        __syncthreads();
    }
    if (i < n) incl[i] = sd[t];
    if (t == 255) bsum[blockIdx.x] = sd[255];
}

__global__ void k_scan_bsum(int* __restrict__ bsum, int nb) {
    __shared__ int sd[256];
    int t = threadIdx.x;
    int v = (t < nb) ? bsum[t] : 0;
    sd[t] = v;
    __syncthreads();
    for (int off = 1; off < 256; off <<= 1) {
        int add = (t >= off) ? sd[t - off] : 0;
        __syncthreads();
        sd[t] += add;
        __syncthreads();
    }
    if (t < nb) bsum[t] = sd[t] - v;
}

__global__ void k_rowptr(const int* __restrict__ incl, const int* __restrict__ deg,
                         const int* __restrict__ boff, int* __restrict__ row_ptr,
                         int* __restrict__ cursor, int n, int total) {
    int i = blockIdx.x * blockDim.x + threadIdx.x;
    if (i < n) {
        row_ptr[i] = incl[i] - deg[i] + boff[i >> 8];
        cursor[i] = 0;
    }
    if (i == 0) row_ptr[n] = total;
}

__global__ void k_scatter(const int* __restrict__ ei, int E, int E2,
                          const int* __restrict__ row_ptr, int* __restrict__ cursor,
                          int* __restrict__ csr_src) {
    int e = blockIdx.x * blockDim.x + threadIdx.x;
    if (e >= E2) return;
    int se, de;
    if (e < E) { se = ei[e]; de = ei[E + e]; }
    else       { se = e - E; de = se; }
    int pos = atomicAdd(&cursor[de], 1);
    csr_src[row_ptr[de] + pos] = se;
}

// ---- aggregation v5.1: 2 nodes/wave, 32 lanes/node, idx-prefetch pipeline ----
__global__ __launch_bounds__(256) void k_aggregate(const _Float16* __restrict__ hmat,
        const int* __restrict__ row_ptr, const int* __restrict__ csr_src,
        const float* __restrict__ alpha_src, const float* __restrict__ alpha_dst,
        const float* __restrict__ bias, float* __restrict__ outf,
        _Float16* __restrict__ outx, int relu, int nrows) {
    int wid  = (blockIdx.x * 256 + threadIdx.x) >> 6;
    int lane = threadIdx.x & 63;
    int node = wid * 2 + (lane >> 5);      // 2 nodes per wave
    if (node >= nrows) return;
    int c    = lane & 31;                  // channel octet: channels c*8..c*8+7
    int head = c >> 3;
    int st = row_ptr[node], en = row_ptr[node + 1];
    int deg = en - st;
    int nbatch = (deg + 7) >> 3;
    float a_d = alpha_dst[node * 4 + head];
    float acc[8] = {};
    float ssum = 0.f;
    int sn[8];
    #pragma unroll
    for (int j = 0; j < 8; ++j) {
        int li = st + (j < deg ? j : deg - 1);
        sn[j] = csr_src[li];
    }
    for (int b = 0; b < nbatch; ++b) {
        f16x8 hv[8];
        #pragma unroll
        for (int j = 0; j < 8; ++j)
            hv[j] = *(const f16x8*)&hmat[(size_t)sn[j] * D + c * 8];
        float as[8];
        #pragma unroll
        for (int j = 0; j < 8; ++j) as[j] = alpha_src[sn[j] * 4 + head];
        int sn2[8];
        if (b + 1 < nbatch) {
            #pragma unroll
            for (int j = 0; j < 8; ++j) {
                int e = (b + 1) * 8 + j;
                int li = st + (e < deg ? e : deg - 1);
                sn2[j] = csr_src[li];
            }
        }
        #pragma unroll
        for (int j = 0; j < 8; ++j) {
            float a = as[j] + a_d;
            a = a > 0.f ? a : NEG_SLOPE * a;
            float ex = (b * 8 + j < deg) ? __expf(a) : 0.f;
            ssum += ex;
            #pragma unroll
            for (int k = 0; k < 8; ++k) acc[k] += ex * (float)hv[j][k];
        }
        #pragma unroll
        for (int j = 0; j < 8; ++j) sn[j] = sn2[j];
    }
    float sinv = 1.f / (ssum + 1e-16f);
    float4 b0 = *(const float4*)&bias[c * 8];
    float4 b1 = *(const float4*)&bias[c * 8 + 4];
    float o[8];
    o[0] = acc[0] * sinv + b0.x; o[1] = acc[1] * sinv + b0.y;
    o[2] = acc[2] * sinv + b0.z; o[3] = acc[3] * sinv + b0.w;
    o[4] = acc[4] * sinv + b1.x; o[5] = acc[5] * sinv + b1.y;
    o[6] = acc[6] * sinv + b1.z; o[7] = acc[7] * sinv + b1.w;
    if (relu) {
        #pragma unroll
        for (int k = 0; k < 8; ++k) o[k] = fmaxf(o[k], 0.f);
    }
    if (outx) {
        f16x8 o8 = {(_Float16)o[0], (_Float16)o[1], (_Float16)o[2], (_Float16)o[3],
                    (_Float16)o[4], (_Float16)o[5], (_Float16)o[6], (_Float16)o[7]};
        *(f16x8*)&outx[(size_t)node * D + c * 8] = o8;
    } else {
        *(float4*)&outf[(size_t)node * D + c * 8] =
            make_float4(o[0], o[1], o[2], o[3]);
        *(float4*)&outf[(size_t)node * D + c * 8 + 4] =
            make_float4(o[4], o[5], o[6], o[7]);
    }
}

extern "C" void kernel_launch(void* const* d_in, const int* in_sizes, int n_in,
                              void* d_out, int out_size, void* d_ws, size_t ws_size,
                              hipStream_t stream) {
    const float* x = (const float*)d_in[0];
    const int* ei = (const int*)d_in[1];
    const int N  = in_sizes[0] / 128;   // 50000
    const int E  = in_sizes[1] / 2;     // 400000
    const int E2 = E + N;               // + self loops

    char* wsp = (char*)d_ws;
    size_t off = 0;
    auto alloc = [&](size_t bytes) -> void* {
        void* p = wsp + off;
        off += (bytes + 255) & ~(size_t)255;
        return p;
    };
    _Float16* bufH  = (_Float16*)alloc((size_t)N * D * 2);     // 25.6 MB
    _Float16* xf16  = (_Float16*)alloc((size_t)N * D * 2);     // 25.6 MB
    _Float16* wfrag = (_Float16*)alloc((size_t)(128 * 256 + 4 * 256 * 256) * 2);
    float* alpha_src = (float*)alloc((size_t)N * H * 4);
    float* alpha_dst = (float*)alloc((size_t)N * H * 4);
    int*   deg       = (int*)alloc((size_t)N * 4);
    int*   incl      = (int*)alloc((size_t)N * 4);
    int*   bsum      = (int*)alloc(256 * 4);
    int*   row_ptr   = (int*)alloc((size_t)(N + 1) * 4);
    int*   cursor    = (int*)alloc((size_t)N * 4);
    int*   csr_src   = (int*)alloc((size_t)E2 * 4);
    (void)ws_size;

    hipMemsetAsync(deg, 0, (size_t)N * 4, stream);

    // W -> fragment layout (layer 0 + merged layers 1-4)
    k_cvt_wfrag0<<<(16 * 4 * 64 + 255) / 256, 256, 0, stream>>>(
        (const float*)d_in[2], wfrag);
    dim3 wg((16 * 8 * 64 + 255) / 256, 4);
    k_cvt_wfrag_all<<<wg, 256, 0, stream>>>(
        (const float*)d_in[6], (const float*)d_in[10],
        (const float*)d_in[14], (const float*)d_in[18], wfrag);

    // CSR by dst
    int egrid = (E2 + 255) / 256;
    k_deg<<<egrid, 256, 0, stream>>>(ei, E, E2, deg);
    int nb = (N + 255) / 256;
    k_scan_block<<<nb, 256, 0, stream>>>(deg, incl, bsum, N);
    k_scan_bsum<<<1, 256, 0, stream>>>(bsum, nb);
    k_rowptr<<<nb, 256, 0, stream>>>(incl, deg, bsum, row_ptr, cursor, N, E2);
    k_scatter<<<egrid, 256, 0, stream>>>(ei, E, E2, row_ptr, cursor, csr_src);

    int nchunk = (N + 63) / 64;
    int ggrid = nchunk * 4;             // 4 col-splits (heads), XCD-pinned decode
    int agrid = (N + 7) / 8;            // 4 waves x 2 nodes per block
    for (int l = 0; l < 5; ++l) {
        const float* as_ = (const float*)d_in[3 + 4 * l];
        const float* ad_ = (const float*)d_in[4 + 4 * l];
        const float* bs_ = (const float*)d_in[5 + 4 * l];
        const _Float16* wl = (l == 0) ? wfrag
                           : wfrag + 128 * 256 + (size_t)(l - 1) * 256 * 256;

        if (l == 0)
            k_gemm_mfma<128, true><<<ggrid, 256, 0, stream>>>(x, wl, as_, ad_,
                                                        bufH, alpha_src, alpha_dst, N, nchunk);
        else
            k_gemm_mfma<256, false><<<ggrid, 256, 0, stream>>>(xf16, wl, as_, ad_,
                                                        bufH, alpha_src, alpha_dst, N, nchunk);

        int last = (l == 4);
        k_aggregate<<<agrid, 256, 0, stream>>>(bufH, row_ptr, csr_src,
                                               alpha_src, alpha_dst, bs_,
                                               last ? (float*)d_out : nullptr,
                                               last ? nullptr : xf16,
                                               last ? 0 : 1, N);
    }
}